// Round 21
// baseline (264.891 us; speedup 1.0000x reference)
//
#include <hip/hip_runtime.h>

#define DIM 64
#define TWO_DIM 128
#define NR 512     // node ranges (one k_build block each; ~2 blocks/CU)
#define BCAP 28    // per-(block,range) bucket capacity (lambda=6.1)
#define NWB 512    // bucketing blocks

typedef __attribute__((ext_vector_type(8))) short bf16x8;
typedef __attribute__((ext_vector_type(4))) float f32x4;
#define MFMA16(A, B, C) __builtin_amdgcn_mfma_f32_16x16x32_bf16(A, B, C, 0, 0, 0)

__device__ __forceinline__ float fast_tanh(float x) {
  float cx = fminf(fmaxf(x, -15.0f), 15.0f);
  float e = __expf(2.0f * cx);
  return (e - 1.0f) / (e + 1.0f);
}

__device__ __forceinline__ unsigned short f2bf(float x) {
  unsigned int b = __float_as_uint(x);
  unsigned int r = b + 0x7FFFu + ((b >> 16) & 1u);
  return (unsigned short)(r >> 16);
}
__device__ __forceinline__ float bf2f(unsigned short h) {
  return __uint_as_float(((unsigned int)h) << 16);
}
__device__ __forceinline__ uint4 pack8(const unsigned short* s) {
  uint4 u;
  u.x = (unsigned)s[0] | ((unsigned)s[1] << 16);
  u.y = (unsigned)s[2] | ((unsigned)s[3] << 16);
  u.z = (unsigned)s[4] | ((unsigned)s[5] << 16);
  u.w = (unsigned)s[6] | ((unsigned)s[7] << 16);
  return u;
}

__device__ __forceinline__ void prepw_one(const float* __restrict__ W1,
                                          const float* __restrict__ W2,
                                          uint4* __restrict__ w1h, uint4* __restrict__ w1l,
                                          uint4* __restrict__ w2h, uint4* __restrict__ w2l,
                                          int p) {
  int lane = p & 63;
  int c = lane & 15, g = lane >> 4;
  unsigned short hh[8], ll[8];
  if (p < 1024) {
    int nt = p >> 7, f = (p >> 6) & 1;
    int nn = nt * 16 + c, kb = f * 32 + g * 8;
#pragma unroll
    for (int e = 0; e < 8; ++e) {
      float w = W1[(kb + e) * TWO_DIM + nn];
      hh[e] = f2bf(w);
      ll[e] = f2bf(w - bf2f(hh[e]));
    }
    w1h[p] = pack8(hh);
    w1l[p] = pack8(ll);
  } else {
    int q = p - 1024;
    int nt = q >> 8, f = (q >> 6) & 3;
    int nn = nt * 16 + c, kb = f * 32 + g * 8;
#pragma unroll
    for (int e = 0; e < 8; ++e) {
      float w = W2[(kb + e) * DIM + nn];
      hh[e] = f2bf(w);
      ll[e] = f2bf(w - bf2f(hh[e]));
    }
    w2h[q] = pack8(hh);
    w2l[q] = pack8(ll);
  }
}

// Front kernel: blocks [0,NWB) bucket edges into 512 ranges (packed
// src<<9|dstlocal; cnts stored TRANSPOSED cnts_t[r*NWB+wb] for coalesced
// k_build reads); [NWB,NWB+18) setup; rest fp32->bf16 conversion.
__global__ void k_front(const int* __restrict__ src, const int* __restrict__ dst,
                        unsigned* __restrict__ regions, int* __restrict__ cnts_t,
                        int* __restrict__ spilln, uint2* __restrict__ spill,
                        int E, int n,
                        const float* __restrict__ x, unsigned short* __restrict__ xb,
                        int N4,
                        const float* __restrict__ W11, const float* __restrict__ W12,
                        const float* __restrict__ W21, const float* __restrict__ W22,
                        const float* __restrict__ b11, const float* __restrict__ g1,
                        const float* __restrict__ be1, const float* __restrict__ b21,
                        const float* __restrict__ g2, const float* __restrict__ be2,
                        const int* __restrict__ batch,
                        uint4* __restrict__ w1hA, uint4* __restrict__ w1lA,
                        uint4* __restrict__ w2hA, uint4* __restrict__ w2lA,
                        uint4* __restrict__ w1hB, uint4* __restrict__ w1lB,
                        uint4* __restrict__ w2hB, uint4* __restrict__ w2lB,
                        float* __restrict__ sc1, float* __restrict__ sh1,
                        float* __restrict__ sc2, float* __restrict__ sh2,
                        int* __restrict__ cnt) {
  __shared__ int bcnt[NR];
  __shared__ int lb[257];
  const int b = blockIdx.x;
  const int t = threadIdx.x;

  if (b < NWB) {
    bcnt[t] = 0;
    bcnt[t + 256] = 0;
    __syncthreads();
    const int RS = (n + NR - 1) / NR;  // 196
    int tid = b * 256 + t;
    int stride = NWB * 256;
    int E4 = E >> 2;
    const int4* s4 = reinterpret_cast<const int4*>(src);
    const int4* d4 = reinterpret_cast<const int4*>(dst);
    unsigned* myreg = regions + (size_t)b * NR * BCAP;
    for (int i = tid; i < E4; i += stride) {
      int4 s = s4[i];
      int4 d = d4[i];
#pragma unroll
      for (int e = 0; e < 4; ++e) {
        int de = (e == 0) ? d.x : (e == 1) ? d.y : (e == 2) ? d.z : d.w;
        int se = (e == 0) ? s.x : (e == 1) ? s.y : (e == 2) ? s.z : s.w;
        int r = (unsigned)de / (unsigned)RS;
        int pos = atomicAdd(&bcnt[r], 1);
        if (pos < BCAP)
          myreg[r * BCAP + pos] =
              ((unsigned)se << 9) | (unsigned)(de - r * RS);
        else {
          int sp = atomicAdd(spilln, 1);
          spill[sp] = make_uint2((unsigned)se, (unsigned)de);
        }
      }
    }
    if (tid == 0) {
      for (int i = E4 << 2; i < E; ++i) {
        int sp = atomicAdd(spilln, 1);
        spill[sp] = make_uint2((unsigned)src[i], (unsigned)dst[i]);
      }
    }
    __syncthreads();
    cnts_t[(size_t)t * NWB + b] = min(bcnt[t], BCAP);
    cnts_t[(size_t)(t + 256) * NWB + b] = min(bcnt[t + 256], BCAP);
  } else if (b < NWB + 8) {
    prepw_one(W11, W12, w1hA, w1lA, w2hA, w2lA, (b - NWB) * 256 + t);
  } else if (b < NWB + 16) {
    prepw_one(W21, W22, w1hB, w1lB, w2hB, w2lB, (b - NWB - 8) * 256 + t);
  } else if (b == NWB + 16) {
    float rs = rsqrtf(1.0f + 1e-5f);
    if (t < TWO_DIM) {
      float s = g1[t] * rs;
      sc1[t] = s;
      sh1[t] = b11[t] * s + be1[t];
    } else {
      int i = t - TWO_DIM;
      float s = g2[i] * rs;
      sc2[i] = s;
      sh2[i] = b21[i] * s + be2[i];
    }
  } else if (b == NWB + 17) {
    int lo = 0, hi = n;
    while (lo < hi) {
      int mid = (lo + hi) >> 1;
      if (batch[mid] < t) lo = mid + 1; else hi = mid;
    }
    lb[t] = lo;
    if (t == 0) lb[256] = n;
    __syncthreads();
    cnt[t] = lb[t + 1] - lb[t];
  } else {
    int base = (b - NWB - 18) * 256 + t;
    int stride = (gridDim.x - NWB - 18) * 256;
    for (int i = base; i < N4; i += stride) {
      float4 f = reinterpret_cast<const float4*>(x)[i];
      ushort4 u;
      u.x = f2bf(f.x);
      u.y = f2bf(f.y);
      u.z = f2bf(f.z);
      u.w = f2bf(f.w);
      reinterpret_cast<ushort4*>(xb)[i] = u;
    }
  }
}

// One block per range (512 blocks -> ~2/CU). Coalesced cnts_t reads; inline
// rtot; LDS CSR build. Blocks >= NR zero `pooled`.
__launch_bounds__(1024, 8)
__global__ void k_build(const unsigned* __restrict__ regions, const int* __restrict__ cnts_t,
                        const int* __restrict__ spilln, const uint2* __restrict__ spill,
                        int* __restrict__ deg, int* __restrict__ offs,
                        int* __restrict__ csr, float* __restrict__ pooled, int n) {
  if (blockIdx.x >= NR) {
    int i = (blockIdx.x - NR) * 1024 + threadIdx.x;
    pooled[i] = 0.0f;
    return;
  }
  __shared__ unsigned lbuf[4096];  // 16 KB
  __shared__ int ccnt[NWB];
  __shared__ int co[NWB];
  __shared__ int ps[1024];
  __shared__ int tot[NR];
  __shared__ int sscan[NR];
  __shared__ int ldeg[200];
  __shared__ int lcur[200];
  __shared__ int sTr;
  const int r = blockIdx.x;
  const int RS = (n + NR - 1) / NR;  // 196
  const int lo = r * RS;
  const int hi = min(n, lo + RS);
  const int len = hi - lo;
  int t = threadIdx.x;

  // ---- inline rtot (coalesced: cnts_t rows are contiguous in wb)
  {
    int rr = t & 511, q = t >> 9;  // q in {0,1}
    const int* row = cnts_t + (size_t)rr * NWB + q * (NWB / 2);
    int sum = 0;
#pragma unroll 8
    for (int wb = 0; wb < NWB / 2; ++wb) sum += row[wb];
    ps[t] = sum;
    __syncthreads();
    if (t < NR) tot[t] = ps[t] + ps[t + 512];
    __syncthreads();
    if (t == 0) {
      int sn = *spilln;
      for (int i = 0; i < sn; ++i) tot[spill[i].y / (unsigned)RS]++;
    }
    __syncthreads();
    if (t < NR) sscan[t] = tot[t];
    __syncthreads();
    for (int off = 1; off < NR; off <<= 1) {
      int u = (t >= off && t < NR) ? sscan[t - off] : 0;
      __syncthreads();
      if (t < NR) sscan[t] += u;
      __syncthreads();
    }
  }
  const int myrbase = sscan[r] - tot[r];
  __syncthreads();

  if (t < NWB) ccnt[t] = cnts_t[(size_t)r * NWB + t];  // coalesced
  __syncthreads();
  int own = (t < NWB) ? ccnt[t] : 0;
  ps[t] = own;
  __syncthreads();
  for (int off = 1; off < 1024; off <<= 1) {
    int u = (t >= off) ? ps[t - off] : 0;
    __syncthreads();
    ps[t] += u;
    __syncthreads();
  }
  if (t < NWB) co[t] = ps[t] - own;
  int total = ps[1023];
  __syncthreads();

  const int wave = t >> 6, lane = t & 63;
  for (int wb = wave; wb < NWB; wb += 16) {
    int c = ccnt[wb];
    const unsigned* reg = regions + ((size_t)wb * NR + r) * BCAP;
    int o = co[wb];
    for (int i = lane; i < c; i += 64) lbuf[o + i] = reg[i];
  }
  if (t == 0) {
    int Tr = total;
    int sn = *spilln;
    for (int i = 0; i < sn; ++i) {
      uint2 e = spill[i];
      int dv = (int)e.y;
      if (dv >= lo && dv < hi && Tr < 4096)
        lbuf[Tr++] = (e.x << 9) | (unsigned)(dv - lo);
    }
    sTr = Tr;
  }
  if (t < len) ldeg[t] = 0;
  __syncthreads();
  const int Tr = sTr;

  for (int i = t; i < Tr; i += 1024) atomicAdd(&ldeg[lbuf[i] & 511u], 1);
  __syncthreads();

  int d = (t < len) ? ldeg[t] : 0;
  ps[t] = d;
  __syncthreads();
  for (int off = 1; off < 1024; off <<= 1) {
    int u = (t >= off) ? ps[t - off] : 0;
    __syncthreads();
    ps[t] += u;
    __syncthreads();
  }
  int base = myrbase + ps[t] - d;
  if (t < len) {
    offs[lo + t] = base;
    deg[lo + t] = d;
    lcur[t] = base;
  }
  __syncthreads();

  for (int i = t; i < Tr; i += 1024) {
    unsigned e = lbuf[i];
    int p = atomicAdd(&lcur[e & 511u], 1);
    csr[p] = (int)(e >> 9);
  }
}

// Gather + GIN pre-sum from bf16 rows, scalarized index stream.
__global__ void k_gatherv(const unsigned short* __restrict__ xb,
                          const int* __restrict__ csr, const int* __restrict__ offs,
                          const int* __restrict__ deg, const float* __restrict__ epsp,
                          float* __restrict__ v, int n, int npad) {
  int node = __builtin_amdgcn_readfirstlane(blockIdx.x * 4 + (threadIdx.x >> 6));
  int t = threadIdx.x & 63;
  if (node >= npad) return;
  if (node >= n) {
    v[(size_t)node * DIM + t] = 0.0f;
    return;
  }
  int s = offs[node], d = deg[node];
  float a0 = 0.f, a1 = 0.f, a2 = 0.f, a3 = 0.f;
  float a4 = 0.f, a5 = 0.f, a6 = 0.f, a7 = 0.f;
  int i = 0;
  for (; i + 16 <= d; i += 16) {
    int s0 = csr[s + i + 0];
    int s1 = csr[s + i + 1];
    int s2 = csr[s + i + 2];
    int s3 = csr[s + i + 3];
    int s4 = csr[s + i + 4];
    int s5 = csr[s + i + 5];
    int s6 = csr[s + i + 6];
    int s7 = csr[s + i + 7];
    int s8 = csr[s + i + 8];
    int s9 = csr[s + i + 9];
    int sa = csr[s + i + 10];
    int sb = csr[s + i + 11];
    int sc = csr[s + i + 12];
    int sd = csr[s + i + 13];
    int se = csr[s + i + 14];
    int sf = csr[s + i + 15];
    unsigned short w0 = xb[(size_t)s0 * DIM + t];
    unsigned short w1 = xb[(size_t)s1 * DIM + t];
    unsigned short w2 = xb[(size_t)s2 * DIM + t];
    unsigned short w3 = xb[(size_t)s3 * DIM + t];
    unsigned short w4 = xb[(size_t)s4 * DIM + t];
    unsigned short w5 = xb[(size_t)s5 * DIM + t];
    unsigned short w6 = xb[(size_t)s6 * DIM + t];
    unsigned short w7 = xb[(size_t)s7 * DIM + t];
    unsigned short w8 = xb[(size_t)s8 * DIM + t];
    unsigned short w9 = xb[(size_t)s9 * DIM + t];
    unsigned short wa = xb[(size_t)sa * DIM + t];
    unsigned short wb = xb[(size_t)sb * DIM + t];
    unsigned short wc = xb[(size_t)sc * DIM + t];
    unsigned short wd = xb[(size_t)sd * DIM + t];
    unsigned short we = xb[(size_t)se * DIM + t];
    unsigned short wf = xb[(size_t)sf * DIM + t];
    a0 += bf2f(w0); a1 += bf2f(w1); a2 += bf2f(w2); a3 += bf2f(w3);
    a4 += bf2f(w4); a5 += bf2f(w5); a6 += bf2f(w6); a7 += bf2f(w7);
    a0 += bf2f(w8); a1 += bf2f(w9); a2 += bf2f(wa); a3 += bf2f(wb);
    a4 += bf2f(wc); a5 += bf2f(wd); a6 += bf2f(we); a7 += bf2f(wf);
  }
  if (i + 8 <= d) {
    int s0 = csr[s + i + 0];
    int s1 = csr[s + i + 1];
    int s2 = csr[s + i + 2];
    int s3 = csr[s + i + 3];
    int s4 = csr[s + i + 4];
    int s5 = csr[s + i + 5];
    int s6 = csr[s + i + 6];
    int s7 = csr[s + i + 7];
    unsigned short w0 = xb[(size_t)s0 * DIM + t];
    unsigned short w1 = xb[(size_t)s1 * DIM + t];
    unsigned short w2 = xb[(size_t)s2 * DIM + t];
    unsigned short w3 = xb[(size_t)s3 * DIM + t];
    unsigned short w4 = xb[(size_t)s4 * DIM + t];
    unsigned short w5 = xb[(size_t)s5 * DIM + t];
    unsigned short w6 = xb[(size_t)s6 * DIM + t];
    unsigned short w7 = xb[(size_t)s7 * DIM + t];
    a0 += bf2f(w0); a1 += bf2f(w1); a2 += bf2f(w2); a3 += bf2f(w3);
    a4 += bf2f(w4); a5 += bf2f(w5); a6 += bf2f(w6); a7 += bf2f(w7);
    i += 8;
  }
  if (i + 4 <= d) {
    int s0 = csr[s + i + 0];
    int s1 = csr[s + i + 1];
    int s2 = csr[s + i + 2];
    int s3 = csr[s + i + 3];
    unsigned short w0 = xb[(size_t)s0 * DIM + t];
    unsigned short w1 = xb[(size_t)s1 * DIM + t];
    unsigned short w2 = xb[(size_t)s2 * DIM + t];
    unsigned short w3 = xb[(size_t)s3 * DIM + t];
    a0 += bf2f(w0); a1 += bf2f(w1); a2 += bf2f(w2); a3 += bf2f(w3);
    i += 4;
  }
  for (; i < d; ++i) {
    int sn = csr[s + i];
    a0 += bf2f(xb[(size_t)sn * DIM + t]);
  }
  float ep = 1.0f + epsp[0];
  v[(size_t)node * DIM + t] =
      ep * bf2f(xb[(size_t)node * DIM + t]) +
      (((a0 + a1) + (a2 + a3)) + ((a4 + a5) + (a6 + a7)));
}

// Fused GIN MLP (unchanged).
template <bool POOL>
__launch_bounds__(256, 2)
__global__ void k_fused(const float* __restrict__ vbuf,
                        const uint4* __restrict__ w1h, const uint4* __restrict__ w1l,
                        const uint4* __restrict__ w2h, const uint4* __restrict__ w2l,
                        const float* __restrict__ sc, const float* __restrict__ sh,
                        const float* __restrict__ b2, unsigned short* __restrict__ houtb,
                        float* __restrict__ pooled, const int* __restrict__ batch,
                        int n, int NTiles) {
  __shared__ uint4 sB1h[1024], sB1l[1024];
  __shared__ uint4 sB2h[1024], sB2l[1024];
  __shared__ float ssc[TWO_DIM], ssh[TWO_DIM], sb2[DIM];
  __shared__ float sHc[4][16 * 36];

  int t = threadIdx.x;
#pragma unroll
  for (int q = 0; q < 4; ++q) {
    sB1h[q * 256 + t] = w1h[q * 256 + t];
    sB1l[q * 256 + t] = w1l[q * 256 + t];
    sB2h[q * 256 + t] = w2h[q * 256 + t];
    sB2l[q * 256 + t] = w2l[q * 256 + t];
  }
  if (t < TWO_DIM) {
    ssc[t] = sc[t];
    ssh[t] = sh[t];
  }
  if (t < DIM) sb2[t] = b2[t];
  __syncthreads();

  const int wid = t >> 6, lane = t & 63;
  const int T = blockIdx.x * 4 + wid;
  if (T >= NTiles) return;
  const int c = lane & 15, g = lane >> 4;

  bf16x8 vah0, vah1, val0, val1;
  {
    const float* vr = vbuf + (size_t)(T * 16 + c) * DIM + g * 8;
    float4 q0 = *reinterpret_cast<const float4*>(vr);
    float4 q1 = *reinterpret_cast<const float4*>(vr + 4);
    float4 q2 = *reinterpret_cast<const float4*>(vr + 32);
    float4 q3 = *reinterpret_cast<const float4*>(vr + 36);
    float f0[8] = {q0.x, q0.y, q0.z, q0.w, q1.x, q1.y, q1.z, q1.w};
    float f1[8] = {q2.x, q2.y, q2.z, q2.w, q3.x, q3.y, q3.z, q3.w};
    unsigned short h0[8], l0[8], h1[8], l1[8];
#pragma unroll
    for (int e = 0; e < 8; ++e) {
      h0[e] = f2bf(f0[e]);
      l0[e] = f2bf(f0[e] - bf2f(h0[e]));
      h1[e] = f2bf(f1[e]);
      l1[e] = f2bf(f1[e] - bf2f(h1[e]));
    }
    uint4 u0 = pack8(h0), u1 = pack8(h1), u2 = pack8(l0), u3 = pack8(l1);
    vah0 = *reinterpret_cast<bf16x8*>(&u0);
    vah1 = *reinterpret_cast<bf16x8*>(&u1);
    val0 = *reinterpret_cast<bf16x8*>(&u2);
    val1 = *reinterpret_cast<bf16x8*>(&u3);
  }

  const bf16x8* B1h = reinterpret_cast<const bf16x8*>(sB1h);
  const bf16x8* B1l = reinterpret_cast<const bf16x8*>(sB1l);
  const bf16x8* B2h = reinterpret_cast<const bf16x8*>(sB2h);
  const bf16x8* B2l = reinterpret_cast<const bf16x8*>(sB2l);
  float* myH = &sHc[wid][0];

  bf16x8 hhf[4], hlf[4];
#pragma unroll
  for (int f2 = 0; f2 < 4; ++f2) {
#pragma unroll
    for (int q = 0; q < 2; ++q) {
      int nt = 2 * f2 + q;
      f32x4 acc = {0.f, 0.f, 0.f, 0.f};
      bf16x8 bh0 = B1h[(nt * 2 + 0) * 64 + lane];
      bf16x8 bl0 = B1l[(nt * 2 + 0) * 64 + lane];
      bf16x8 bh1 = B1h[(nt * 2 + 1) * 64 + lane];
      bf16x8 bl1 = B1l[(nt * 2 + 1) * 64 + lane];
      acc = MFMA16(vah0, bh0, acc);
      acc = MFMA16(vah1, bh1, acc);
      acc = MFMA16(vah0, bl0, acc);
      acc = MFMA16(vah1, bl1, acc);
      acc = MFMA16(val0, bh0, acc);
      acc = MFMA16(val1, bh1, acc);
      int j = nt * 16 + c;
      float scj = ssc[j], shj = ssh[j];
#pragma unroll
      for (int r = 0; r < 4; ++r)
        myH[(g * 4 + r) * 36 + q * 16 + c] = fast_tanh(acc[r] * scj + shj);
    }
    const float* hp = myH + c * 36 + g * 8;
    float4 v0 = *reinterpret_cast<const float4*>(hp);
    float4 v1 = *reinterpret_cast<const float4*>(hp + 4);
    float vv[8] = {v0.x, v0.y, v0.z, v0.w, v1.x, v1.y, v1.z, v1.w};
    unsigned short H8[8], L8[8];
#pragma unroll
    for (int e = 0; e < 8; ++e) {
      H8[e] = f2bf(vv[e]);
      L8[e] = f2bf(vv[e] - bf2f(H8[e]));
    }
    uint4 uh = pack8(H8), ul = pack8(L8);
    hhf[f2] = *reinterpret_cast<bf16x8*>(&uh);
    hlf[f2] = *reinterpret_cast<bf16x8*>(&ul);
  }

  bool uni = false;
  int b0 = 0;
  if (POOL) {
    b0 = batch[min(T * 16, n - 1)];
    int b15 = batch[min(T * 16 + 15, n - 1)];
    uni = (b0 == b15) && (T * 16 + 15 < n);
  }

#pragma unroll
  for (int nt = 0; nt < 4; ++nt) {
    f32x4 acc = {0.f, 0.f, 0.f, 0.f};
    bf16x8 bh0 = B2h[(nt * 4 + 0) * 64 + lane];
    bf16x8 bh1 = B2h[(nt * 4 + 1) * 64 + lane];
    bf16x8 bh2 = B2h[(nt * 4 + 2) * 64 + lane];
    bf16x8 bh3 = B2h[(nt * 4 + 3) * 64 + lane];
    bf16x8 bl0 = B2l[(nt * 4 + 0) * 64 + lane];
    bf16x8 bl1 = B2l[(nt * 4 + 1) * 64 + lane];
    bf16x8 bl2 = B2l[(nt * 4 + 2) * 64 + lane];
    bf16x8 bl3 = B2l[(nt * 4 + 3) * 64 + lane];
    acc = MFMA16(hhf[0], bh0, acc);
    acc = MFMA16(hhf[1], bh1, acc);
    acc = MFMA16(hhf[2], bh2, acc);
    acc = MFMA16(hhf[3], bh3, acc);
    acc = MFMA16(hhf[0], bl0, acc);
    acc = MFMA16(hhf[1], bl1, acc);
    acc = MFMA16(hhf[2], bl2, acc);
    acc = MFMA16(hhf[3], bl3, acc);
    acc = MFMA16(hlf[0], bh0, acc);
    acc = MFMA16(hlf[1], bh1, acc);
    acc = MFMA16(hlf[2], bh2, acc);
    acc = MFMA16(hlf[3], bh3, acc);

    int j = nt * 16 + c;
    float bj = sb2[j];
    float o0 = fast_tanh(acc[0] + bj);
    float o1 = fast_tanh(acc[1] + bj);
    float o2 = fast_tanh(acc[2] + bj);
    float o3 = fast_tanh(acc[3] + bj);
    if (POOL) {
      if (uni) {
        float os = (o0 + o1) + (o2 + o3);
        os += __shfl_xor(os, 16);
        os += __shfl_xor(os, 32);
        if (g == 0) atomicAdd(&pooled[(size_t)b0 * DIM + j], os);
      } else {
        int mb = T * 16 + g * 4;
#pragma unroll
        for (int r = 0; r < 4; ++r) {
          int m = mb + r;
          float o = (r == 0) ? o0 : (r == 1) ? o1 : (r == 2) ? o2 : o3;
          if (m < n) atomicAdd(&pooled[(size_t)batch[m] * DIM + j], o);
        }
      }
    } else {
      int mb = T * 16 + g * 4;
      if (mb + 0 < n) houtb[(size_t)(mb + 0) * DIM + j] = f2bf(o0);
      if (mb + 1 < n) houtb[(size_t)(mb + 1) * DIM + j] = f2bf(o1);
      if (mb + 2 < n) houtb[(size_t)(mb + 2) * DIM + j] = f2bf(o2);
      if (mb + 3 < n) houtb[(size_t)(mb + 3) * DIM + j] = f2bf(o3);
    }
  }
}

// out[g][i] = tanh( (pooled[g]/max(cnt,1)) . linW[:,i] + linb[i] )
__global__ void k_out(const float* __restrict__ pooled, const int* __restrict__ cnt,
                      const float* __restrict__ linW, const float* __restrict__ linb,
                      float* __restrict__ out) {
  int g = blockIdx.x;
  int i = threadIdx.x;
  int c = cnt[g];
  float inv = 1.0f / (float)(c > 0 ? c : 1);
  float acc = 0.0f;
#pragma unroll
  for (int k = 0; k < DIM; ++k)
    acc += pooled[(size_t)g * DIM + k] * linW[k * DIM + i];
  out[(size_t)g * DIM + i] = fast_tanh(acc * inv + linb[i]);
}

extern "C" void kernel_launch(void* const* d_in, const int* in_sizes, int n_in,
                              void* d_out, int out_size, void* d_ws, size_t ws_size,
                              hipStream_t stream) {
  const float* x = (const float*)d_in[0];
  const int* ei = (const int*)d_in[1];
  const int* batch = (const int*)d_in[2];
  const float* eps1 = (const float*)d_in[3];
  const float* W11 = (const float*)d_in[4];
  const float* b11 = (const float*)d_in[5];
  const float* g1 = (const float*)d_in[6];
  const float* be1 = (const float*)d_in[7];
  const float* W12 = (const float*)d_in[8];
  const float* b12 = (const float*)d_in[9];
  const float* eps2 = (const float*)d_in[10];
  const float* W21 = (const float*)d_in[11];
  const float* b21 = (const float*)d_in[12];
  const float* g2 = (const float*)d_in[13];
  const float* be2 = (const float*)d_in[14];
  const float* W22 = (const float*)d_in[15];
  const float* b22 = (const float*)d_in[16];
  const float* linW = (const float*)d_in[17];
  const float* linb = (const float*)d_in[18];

  const int n = in_sizes[0] / DIM;  // 100000
  const int E = in_sizes[1] / 2;    // 1600000
  const int G = out_size / DIM;     // 256
  const int* src = ei;
  const int* dst = ei + E;
  const int NT = (n + 15) / 16;     // 6250
  const int npad = NT * 16;

  size_t off = 0;
  auto alloc = [&](size_t bytes) -> void* {
    void* p = (char*)d_ws + off;
    off += (bytes + 255) & ~(size_t)255;
    return p;
  };
  unsigned short* xb = (unsigned short*)alloc((size_t)npad * DIM * 2);
  unsigned short* h1b = (unsigned short*)alloc((size_t)npad * DIM * 2);
  float* vbuf = (float*)alloc((size_t)npad * DIM * 4);
  unsigned* regions = (unsigned*)alloc((size_t)NWB * NR * BCAP * 4);
  int* cnts_t = (int*)alloc((size_t)NWB * NR * 4);
  uint2* spill = (uint2*)alloc((size_t)65536 * 8);
  int* spilln = (int*)alloc(256);
  int* deg = (int*)alloc((size_t)n * 4);
  int* offs = (int*)alloc((size_t)n * 4);
  int* csr = (int*)alloc((size_t)E * 4);
  float* sc1 = (float*)alloc(TWO_DIM * 4);
  float* sh1 = (float*)alloc(TWO_DIM * 4);
  float* sc2 = (float*)alloc(TWO_DIM * 4);
  float* sh2 = (float*)alloc(TWO_DIM * 4);
  uint4* w1hA = (uint4*)alloc(1024 * 16);
  uint4* w1lA = (uint4*)alloc(1024 * 16);
  uint4* w2hA = (uint4*)alloc(1024 * 16);
  uint4* w2lA = (uint4*)alloc(1024 * 16);
  uint4* w1hB = (uint4*)alloc(1024 * 16);
  uint4* w1lB = (uint4*)alloc(1024 * 16);
  uint4* w2hB = (uint4*)alloc(1024 * 16);
  uint4* w2lB = (uint4*)alloc(1024 * 16);
  float* pooled = (float*)alloc((size_t)G * DIM * 4);
  int* cnt = (int*)alloc((size_t)G * 4);

  hipMemsetAsync(spilln, 0, 4, stream);

  const int N4 = n * DIM / 4;
  k_front<<<NWB + 18 + 1024, 256, 0, stream>>>(
      src, dst, regions, cnts_t, spilln, spill, E, n, x, xb, N4, W11, W12, W21, W22,
      b11, g1, be1, b21, g2, be2, batch, w1hA, w1lA, w2hA, w2lA, w1hB, w1lB, w2hB,
      w2lB, sc1, sh1, sc2, sh2, cnt);
  k_build<<<NR + 16, 1024, 0, stream>>>(regions, cnts_t, spilln, spill, deg, offs,
                                        csr, pooled, n);

  const int gB = (npad + 3) / 4;
  // GIN layer 1
  k_gatherv<<<gB, 256, 0, stream>>>(xb, csr, offs, deg, eps1, vbuf, n, npad);
  k_fused<false><<<(NT + 3) / 4, 256, 0, stream>>>(vbuf, w1hA, w1lA, w2hA, w2lA,
                                                   sc1, sh1, b12, h1b, nullptr,
                                                   nullptr, n, NT);
  // GIN layer 2
  k_gatherv<<<gB, 256, 0, stream>>>(h1b, csr, offs, deg, eps2, vbuf, n, npad);
  k_fused<true><<<(NT + 3) / 4, 256, 0, stream>>>(vbuf, w1hB, w1lB, w2hB, w2lB,
                                                  sc2, sh2, b22, nullptr, pooled,
                                                  batch, n, NT);
  k_out<<<G, DIM, 0, stream>>>(pooled, cnt, linW, linb, (float*)d_out);
}

// Round 22
// 240.341 us; speedup vs baseline: 1.1021x; 1.1021x over previous
//
#include <hip/hip_runtime.h>

#define DIM 64
#define TWO_DIM 128
#define NR 512     // node ranges (one k_build block each; ~2 blocks/CU)
#define BCAP 28    // per-(block,range) bucket capacity (lambda=6.1)
#define NWB 512    // bucketing blocks

typedef __attribute__((ext_vector_type(8))) short bf16x8;
typedef __attribute__((ext_vector_type(4))) float f32x4;
#define MFMA16(A, B, C) __builtin_amdgcn_mfma_f32_16x16x32_bf16(A, B, C, 0, 0, 0)

__device__ __forceinline__ float fast_tanh(float x) {
  float cx = fminf(fmaxf(x, -15.0f), 15.0f);
  float e = __expf(2.0f * cx);
  return (e - 1.0f) / (e + 1.0f);
}

__device__ __forceinline__ unsigned short f2bf(float x) {
  unsigned int b = __float_as_uint(x);
  unsigned int r = b + 0x7FFFu + ((b >> 16) & 1u);
  return (unsigned short)(r >> 16);
}
__device__ __forceinline__ float bf2f(unsigned short h) {
  return __uint_as_float(((unsigned int)h) << 16);
}
__device__ __forceinline__ uint4 pack8(const unsigned short* s) {
  uint4 u;
  u.x = (unsigned)s[0] | ((unsigned)s[1] << 16);
  u.y = (unsigned)s[2] | ((unsigned)s[3] << 16);
  u.z = (unsigned)s[4] | ((unsigned)s[5] << 16);
  u.w = (unsigned)s[6] | ((unsigned)s[7] << 16);
  return u;
}

__device__ __forceinline__ void prepw_one(const float* __restrict__ W1,
                                          const float* __restrict__ W2,
                                          uint4* __restrict__ w1h, uint4* __restrict__ w1l,
                                          uint4* __restrict__ w2h, uint4* __restrict__ w2l,
                                          int p) {
  int lane = p & 63;
  int c = lane & 15, g = lane >> 4;
  unsigned short hh[8], ll[8];
  if (p < 1024) {
    int nt = p >> 7, f = (p >> 6) & 1;
    int nn = nt * 16 + c, kb = f * 32 + g * 8;
#pragma unroll
    for (int e = 0; e < 8; ++e) {
      float w = W1[(kb + e) * TWO_DIM + nn];
      hh[e] = f2bf(w);
      ll[e] = f2bf(w - bf2f(hh[e]));
    }
    w1h[p] = pack8(hh);
    w1l[p] = pack8(ll);
  } else {
    int q = p - 1024;
    int nt = q >> 8, f = (q >> 6) & 3;
    int nn = nt * 16 + c, kb = f * 32 + g * 8;
#pragma unroll
    for (int e = 0; e < 8; ++e) {
      float w = W2[(kb + e) * DIM + nn];
      hh[e] = f2bf(w);
      ll[e] = f2bf(w - bf2f(hh[e]));
    }
    w2h[q] = pack8(hh);
    w2l[q] = pack8(ll);
  }
}

// Front kernel: blocks [0,NWB) bucket edges into 512 ranges (packed
// src<<9|dstlocal; cnts stored TRANSPOSED cnts_t[r*NWB+wb]); [NWB,NWB+18)
// setup; rest fp32->bf16 conversion.
__global__ void k_front(const int* __restrict__ src, const int* __restrict__ dst,
                        unsigned* __restrict__ regions, int* __restrict__ cnts_t,
                        int* __restrict__ spilln, uint2* __restrict__ spill,
                        int E, int n,
                        const float* __restrict__ x, unsigned short* __restrict__ xb,
                        int N4,
                        const float* __restrict__ W11, const float* __restrict__ W12,
                        const float* __restrict__ W21, const float* __restrict__ W22,
                        const float* __restrict__ b11, const float* __restrict__ g1,
                        const float* __restrict__ be1, const float* __restrict__ b21,
                        const float* __restrict__ g2, const float* __restrict__ be2,
                        const int* __restrict__ batch,
                        uint4* __restrict__ w1hA, uint4* __restrict__ w1lA,
                        uint4* __restrict__ w2hA, uint4* __restrict__ w2lA,
                        uint4* __restrict__ w1hB, uint4* __restrict__ w1lB,
                        uint4* __restrict__ w2hB, uint4* __restrict__ w2lB,
                        float* __restrict__ sc1, float* __restrict__ sh1,
                        float* __restrict__ sc2, float* __restrict__ sh2,
                        int* __restrict__ cnt) {
  __shared__ int bcnt[NR];
  __shared__ int lb[257];
  const int b = blockIdx.x;
  const int t = threadIdx.x;

  if (b < NWB) {
    bcnt[t] = 0;
    bcnt[t + 256] = 0;
    __syncthreads();
    const int RS = (n + NR - 1) / NR;  // 196
    int tid = b * 256 + t;
    int stride = NWB * 256;
    int E4 = E >> 2;
    const int4* s4 = reinterpret_cast<const int4*>(src);
    const int4* d4 = reinterpret_cast<const int4*>(dst);
    unsigned* myreg = regions + (size_t)b * NR * BCAP;
    for (int i = tid; i < E4; i += stride) {
      int4 s = s4[i];
      int4 d = d4[i];
#pragma unroll
      for (int e = 0; e < 4; ++e) {
        int de = (e == 0) ? d.x : (e == 1) ? d.y : (e == 2) ? d.z : d.w;
        int se = (e == 0) ? s.x : (e == 1) ? s.y : (e == 2) ? s.z : s.w;
        int r = (unsigned)de / (unsigned)RS;
        int pos = atomicAdd(&bcnt[r], 1);
        if (pos < BCAP)
          myreg[r * BCAP + pos] =
              ((unsigned)se << 9) | (unsigned)(de - r * RS);
        else {
          int sp = atomicAdd(spilln, 1);
          spill[sp] = make_uint2((unsigned)se, (unsigned)de);
        }
      }
    }
    if (tid == 0) {
      for (int i = E4 << 2; i < E; ++i) {
        int sp = atomicAdd(spilln, 1);
        spill[sp] = make_uint2((unsigned)src[i], (unsigned)dst[i]);
      }
    }
    __syncthreads();
    cnts_t[(size_t)t * NWB + b] = min(bcnt[t], BCAP);
    cnts_t[(size_t)(t + 256) * NWB + b] = min(bcnt[t + 256], BCAP);
  } else if (b < NWB + 8) {
    prepw_one(W11, W12, w1hA, w1lA, w2hA, w2lA, (b - NWB) * 256 + t);
  } else if (b < NWB + 16) {
    prepw_one(W21, W22, w1hB, w1lB, w2hB, w2lB, (b - NWB - 8) * 256 + t);
  } else if (b == NWB + 16) {
    float rs = rsqrtf(1.0f + 1e-5f);
    if (t < TWO_DIM) {
      float s = g1[t] * rs;
      sc1[t] = s;
      sh1[t] = b11[t] * s + be1[t];
    } else {
      int i = t - TWO_DIM;
      float s = g2[i] * rs;
      sc2[i] = s;
      sh2[i] = b21[i] * s + be2[i];
    }
  } else if (b == NWB + 17) {
    int lo = 0, hi = n;
    while (lo < hi) {
      int mid = (lo + hi) >> 1;
      if (batch[mid] < t) lo = mid + 1; else hi = mid;
    }
    lb[t] = lo;
    if (t == 0) lb[256] = n;
    __syncthreads();
    cnt[t] = lb[t + 1] - lb[t];
  } else {
    int base = (b - NWB - 18) * 256 + t;
    int stride = (gridDim.x - NWB - 18) * 256;
    for (int i = base; i < N4; i += stride) {
      float4 f = reinterpret_cast<const float4*>(x)[i];
      ushort4 u;
      u.x = f2bf(f.x);
      u.y = f2bf(f.y);
      u.z = f2bf(f.z);
      u.w = f2bf(f.w);
      reinterpret_cast<ushort4*>(xb)[i] = u;
    }
  }
}

// Range totals + scan -> rbase (1 block, done ONCE; cnts_t rows coalesced).
__global__ void k_rtot(const int* __restrict__ cnts_t, const int* __restrict__ spilln,
                       const uint2* __restrict__ spill, int* __restrict__ rbase,
                       int n) {
  __shared__ int ps[1024];
  __shared__ int tot[NR];
  __shared__ int sscan[NR];
  int t = threadIdx.x;
  int rr = t & 511, q = t >> 9;
  const int* row = cnts_t + (size_t)rr * NWB + q * (NWB / 2);
  int sum = 0;
#pragma unroll 8
  for (int wb = 0; wb < NWB / 2; ++wb) sum += row[wb];
  ps[t] = sum;
  __syncthreads();
  if (t < NR) tot[t] = ps[t] + ps[t + 512];
  __syncthreads();
  if (t == 0) {
    int RS = (n + NR - 1) / NR;
    int sn = *spilln;
    for (int i = 0; i < sn; ++i) tot[spill[i].y / (unsigned)RS]++;
  }
  __syncthreads();
  if (t < NR) sscan[t] = tot[t];
  __syncthreads();
  for (int off = 1; off < NR; off <<= 1) {
    int u = (t >= off && t < NR) ? sscan[t - off] : 0;
    __syncthreads();
    if (t < NR) sscan[t] += u;
    __syncthreads();
  }
  if (t < NR) rbase[t] = sscan[t] - tot[t];
}

// One block per range (512 blocks -> ~2/CU). Coalesced cnts_t reads; reads
// precomputed rbase. Blocks >= NR zero `pooled`.
__launch_bounds__(1024, 8)
__global__ void k_build(const unsigned* __restrict__ regions, const int* __restrict__ cnts_t,
                        const int* __restrict__ spilln, const uint2* __restrict__ spill,
                        const int* __restrict__ rbase, int* __restrict__ deg,
                        int* __restrict__ offs, int* __restrict__ csr,
                        float* __restrict__ pooled, int n) {
  if (blockIdx.x >= NR) {
    int i = (blockIdx.x - NR) * 1024 + threadIdx.x;
    pooled[i] = 0.0f;
    return;
  }
  __shared__ unsigned lbuf[4096];  // 16 KB
  __shared__ int ccnt[NWB];
  __shared__ int co[NWB];
  __shared__ int ps[1024];
  __shared__ int ldeg[200];
  __shared__ int lcur[200];
  __shared__ int sTr;
  const int r = blockIdx.x;
  const int RS = (n + NR - 1) / NR;  // 196
  const int lo = r * RS;
  const int hi = min(n, lo + RS);
  const int len = hi - lo;
  int t = threadIdx.x;
  const int myrbase = rbase[r];

  if (t < NWB) ccnt[t] = cnts_t[(size_t)r * NWB + t];  // coalesced
  __syncthreads();
  int own = (t < NWB) ? ccnt[t] : 0;
  ps[t] = own;
  __syncthreads();
  for (int off = 1; off < 1024; off <<= 1) {
    int u = (t >= off) ? ps[t - off] : 0;
    __syncthreads();
    ps[t] += u;
    __syncthreads();
  }
  if (t < NWB) co[t] = ps[t] - own;
  int total = ps[1023];
  __syncthreads();

  const int wave = t >> 6, lane = t & 63;
  for (int wb = wave; wb < NWB; wb += 16) {
    int c = ccnt[wb];
    const unsigned* reg = regions + ((size_t)wb * NR + r) * BCAP;
    int o = co[wb];
    for (int i = lane; i < c; i += 64) lbuf[o + i] = reg[i];
  }
  if (t == 0) {
    int Tr = total;
    int sn = *spilln;
    for (int i = 0; i < sn; ++i) {
      uint2 e = spill[i];
      int dv = (int)e.y;
      if (dv >= lo && dv < hi && Tr < 4096)
        lbuf[Tr++] = (e.x << 9) | (unsigned)(dv - lo);
    }
    sTr = Tr;
  }
  if (t < len) ldeg[t] = 0;
  __syncthreads();
  const int Tr = sTr;

  for (int i = t; i < Tr; i += 1024) atomicAdd(&ldeg[lbuf[i] & 511u], 1);
  __syncthreads();

  int d = (t < len) ? ldeg[t] : 0;
  ps[t] = d;
  __syncthreads();
  for (int off = 1; off < 1024; off <<= 1) {
    int u = (t >= off) ? ps[t - off] : 0;
    __syncthreads();
    ps[t] += u;
    __syncthreads();
  }
  int base = myrbase + ps[t] - d;
  if (t < len) {
    offs[lo + t] = base;
    deg[lo + t] = d;
    lcur[t] = base;
  }
  __syncthreads();

  for (int i = t; i < Tr; i += 1024) {
    unsigned e = lbuf[i];
    int p = atomicAdd(&lcur[e & 511u], 1);
    csr[p] = (int)(e >> 9);
  }
}

// Gather + GIN pre-sum from bf16 rows, scalarized index stream.
__global__ void k_gatherv(const unsigned short* __restrict__ xb,
                          const int* __restrict__ csr, const int* __restrict__ offs,
                          const int* __restrict__ deg, const float* __restrict__ epsp,
                          float* __restrict__ v, int n, int npad) {
  int node = __builtin_amdgcn_readfirstlane(blockIdx.x * 4 + (threadIdx.x >> 6));
  int t = threadIdx.x & 63;
  if (node >= npad) return;
  if (node >= n) {
    v[(size_t)node * DIM + t] = 0.0f;
    return;
  }
  int s = offs[node], d = deg[node];
  float a0 = 0.f, a1 = 0.f, a2 = 0.f, a3 = 0.f;
  float a4 = 0.f, a5 = 0.f, a6 = 0.f, a7 = 0.f;
  int i = 0;
  for (; i + 16 <= d; i += 16) {
    int s0 = csr[s + i + 0];
    int s1 = csr[s + i + 1];
    int s2 = csr[s + i + 2];
    int s3 = csr[s + i + 3];
    int s4 = csr[s + i + 4];
    int s5 = csr[s + i + 5];
    int s6 = csr[s + i + 6];
    int s7 = csr[s + i + 7];
    int s8 = csr[s + i + 8];
    int s9 = csr[s + i + 9];
    int sa = csr[s + i + 10];
    int sb = csr[s + i + 11];
    int sc = csr[s + i + 12];
    int sd = csr[s + i + 13];
    int se = csr[s + i + 14];
    int sf = csr[s + i + 15];
    unsigned short w0 = xb[(size_t)s0 * DIM + t];
    unsigned short w1 = xb[(size_t)s1 * DIM + t];
    unsigned short w2 = xb[(size_t)s2 * DIM + t];
    unsigned short w3 = xb[(size_t)s3 * DIM + t];
    unsigned short w4 = xb[(size_t)s4 * DIM + t];
    unsigned short w5 = xb[(size_t)s5 * DIM + t];
    unsigned short w6 = xb[(size_t)s6 * DIM + t];
    unsigned short w7 = xb[(size_t)s7 * DIM + t];
    unsigned short w8 = xb[(size_t)s8 * DIM + t];
    unsigned short w9 = xb[(size_t)s9 * DIM + t];
    unsigned short wa = xb[(size_t)sa * DIM + t];
    unsigned short wb = xb[(size_t)sb * DIM + t];
    unsigned short wc = xb[(size_t)sc * DIM + t];
    unsigned short wd = xb[(size_t)sd * DIM + t];
    unsigned short we = xb[(size_t)se * DIM + t];
    unsigned short wf = xb[(size_t)sf * DIM + t];
    a0 += bf2f(w0); a1 += bf2f(w1); a2 += bf2f(w2); a3 += bf2f(w3);
    a4 += bf2f(w4); a5 += bf2f(w5); a6 += bf2f(w6); a7 += bf2f(w7);
    a0 += bf2f(w8); a1 += bf2f(w9); a2 += bf2f(wa); a3 += bf2f(wb);
    a4 += bf2f(wc); a5 += bf2f(wd); a6 += bf2f(we); a7 += bf2f(wf);
  }
  if (i + 8 <= d) {
    int s0 = csr[s + i + 0];
    int s1 = csr[s + i + 1];
    int s2 = csr[s + i + 2];
    int s3 = csr[s + i + 3];
    int s4 = csr[s + i + 4];
    int s5 = csr[s + i + 5];
    int s6 = csr[s + i + 6];
    int s7 = csr[s + i + 7];
    unsigned short w0 = xb[(size_t)s0 * DIM + t];
    unsigned short w1 = xb[(size_t)s1 * DIM + t];
    unsigned short w2 = xb[(size_t)s2 * DIM + t];
    unsigned short w3 = xb[(size_t)s3 * DIM + t];
    unsigned short w4 = xb[(size_t)s4 * DIM + t];
    unsigned short w5 = xb[(size_t)s5 * DIM + t];
    unsigned short w6 = xb[(size_t)s6 * DIM + t];
    unsigned short w7 = xb[(size_t)s7 * DIM + t];
    a0 += bf2f(w0); a1 += bf2f(w1); a2 += bf2f(w2); a3 += bf2f(w3);
    a4 += bf2f(w4); a5 += bf2f(w5); a6 += bf2f(w6); a7 += bf2f(w7);
    i += 8;
  }
  if (i + 4 <= d) {
    int s0 = csr[s + i + 0];
    int s1 = csr[s + i + 1];
    int s2 = csr[s + i + 2];
    int s3 = csr[s + i + 3];
    unsigned short w0 = xb[(size_t)s0 * DIM + t];
    unsigned short w1 = xb[(size_t)s1 * DIM + t];
    unsigned short w2 = xb[(size_t)s2 * DIM + t];
    unsigned short w3 = xb[(size_t)s3 * DIM + t];
    a0 += bf2f(w0); a1 += bf2f(w1); a2 += bf2f(w2); a3 += bf2f(w3);
    i += 4;
  }
  for (; i < d; ++i) {
    int sn = csr[s + i];
    a0 += bf2f(xb[(size_t)sn * DIM + t]);
  }
  float ep = 1.0f + epsp[0];
  v[(size_t)node * DIM + t] =
      ep * bf2f(xb[(size_t)node * DIM + t]) +
      (((a0 + a1) + (a2 + a3)) + ((a4 + a5) + (a6 + a7)));
}

// Fused GIN MLP (unchanged).
template <bool POOL>
__launch_bounds__(256, 2)
__global__ void k_fused(const float* __restrict__ vbuf,
                        const uint4* __restrict__ w1h, const uint4* __restrict__ w1l,
                        const uint4* __restrict__ w2h, const uint4* __restrict__ w2l,
                        const float* __restrict__ sc, const float* __restrict__ sh,
                        const float* __restrict__ b2, unsigned short* __restrict__ houtb,
                        float* __restrict__ pooled, const int* __restrict__ batch,
                        int n, int NTiles) {
  __shared__ uint4 sB1h[1024], sB1l[1024];
  __shared__ uint4 sB2h[1024], sB2l[1024];
  __shared__ float ssc[TWO_DIM], ssh[TWO_DIM], sb2[DIM];
  __shared__ float sHc[4][16 * 36];

  int t = threadIdx.x;
#pragma unroll
  for (int q = 0; q < 4; ++q) {
    sB1h[q * 256 + t] = w1h[q * 256 + t];
    sB1l[q * 256 + t] = w1l[q * 256 + t];
    sB2h[q * 256 + t] = w2h[q * 256 + t];
    sB2l[q * 256 + t] = w2l[q * 256 + t];
  }
  if (t < TWO_DIM) {
    ssc[t] = sc[t];
    ssh[t] = sh[t];
  }
  if (t < DIM) sb2[t] = b2[t];
  __syncthreads();

  const int wid = t >> 6, lane = t & 63;
  const int T = blockIdx.x * 4 + wid;
  if (T >= NTiles) return;
  const int c = lane & 15, g = lane >> 4;

  bf16x8 vah0, vah1, val0, val1;
  {
    const float* vr = vbuf + (size_t)(T * 16 + c) * DIM + g * 8;
    float4 q0 = *reinterpret_cast<const float4*>(vr);
    float4 q1 = *reinterpret_cast<const float4*>(vr + 4);
    float4 q2 = *reinterpret_cast<const float4*>(vr + 32);
    float4 q3 = *reinterpret_cast<const float4*>(vr + 36);
    float f0[8] = {q0.x, q0.y, q0.z, q0.w, q1.x, q1.y, q1.z, q1.w};
    float f1[8] = {q2.x, q2.y, q2.z, q2.w, q3.x, q3.y, q3.z, q3.w};
    unsigned short h0[8], l0[8], h1[8], l1[8];
#pragma unroll
    for (int e = 0; e < 8; ++e) {
      h0[e] = f2bf(f0[e]);
      l0[e] = f2bf(f0[e] - bf2f(h0[e]));
      h1[e] = f2bf(f1[e]);
      l1[e] = f2bf(f1[e] - bf2f(h1[e]));
    }
    uint4 u0 = pack8(h0), u1 = pack8(h1), u2 = pack8(l0), u3 = pack8(l1);
    vah0 = *reinterpret_cast<bf16x8*>(&u0);
    vah1 = *reinterpret_cast<bf16x8*>(&u1);
    val0 = *reinterpret_cast<bf16x8*>(&u2);
    val1 = *reinterpret_cast<bf16x8*>(&u3);
  }

  const bf16x8* B1h = reinterpret_cast<const bf16x8*>(sB1h);
  const bf16x8* B1l = reinterpret_cast<const bf16x8*>(sB1l);
  const bf16x8* B2h = reinterpret_cast<const bf16x8*>(sB2h);
  const bf16x8* B2l = reinterpret_cast<const bf16x8*>(sB2l);
  float* myH = &sHc[wid][0];

  bf16x8 hhf[4], hlf[4];
#pragma unroll
  for (int f2 = 0; f2 < 4; ++f2) {
#pragma unroll
    for (int q = 0; q < 2; ++q) {
      int nt = 2 * f2 + q;
      f32x4 acc = {0.f, 0.f, 0.f, 0.f};
      bf16x8 bh0 = B1h[(nt * 2 + 0) * 64 + lane];
      bf16x8 bl0 = B1l[(nt * 2 + 0) * 64 + lane];
      bf16x8 bh1 = B1h[(nt * 2 + 1) * 64 + lane];
      bf16x8 bl1 = B1l[(nt * 2 + 1) * 64 + lane];
      acc = MFMA16(vah0, bh0, acc);
      acc = MFMA16(vah1, bh1, acc);
      acc = MFMA16(vah0, bl0, acc);
      acc = MFMA16(vah1, bl1, acc);
      acc = MFMA16(val0, bh0, acc);
      acc = MFMA16(val1, bh1, acc);
      int j = nt * 16 + c;
      float scj = ssc[j], shj = ssh[j];
#pragma unroll
      for (int r = 0; r < 4; ++r)
        myH[(g * 4 + r) * 36 + q * 16 + c] = fast_tanh(acc[r] * scj + shj);
    }
    const float* hp = myH + c * 36 + g * 8;
    float4 v0 = *reinterpret_cast<const float4*>(hp);
    float4 v1 = *reinterpret_cast<const float4*>(hp + 4);
    float vv[8] = {v0.x, v0.y, v0.z, v0.w, v1.x, v1.y, v1.z, v1.w};
    unsigned short H8[8], L8[8];
#pragma unroll
    for (int e = 0; e < 8; ++e) {
      H8[e] = f2bf(vv[e]);
      L8[e] = f2bf(vv[e] - bf2f(H8[e]));
    }
    uint4 uh = pack8(H8), ul = pack8(L8);
    hhf[f2] = *reinterpret_cast<bf16x8*>(&uh);
    hlf[f2] = *reinterpret_cast<bf16x8*>(&ul);
  }

  bool uni = false;
  int b0 = 0;
  if (POOL) {
    b0 = batch[min(T * 16, n - 1)];
    int b15 = batch[min(T * 16 + 15, n - 1)];
    uni = (b0 == b15) && (T * 16 + 15 < n);
  }

#pragma unroll
  for (int nt = 0; nt < 4; ++nt) {
    f32x4 acc = {0.f, 0.f, 0.f, 0.f};
    bf16x8 bh0 = B2h[(nt * 4 + 0) * 64 + lane];
    bf16x8 bh1 = B2h[(nt * 4 + 1) * 64 + lane];
    bf16x8 bh2 = B2h[(nt * 4 + 2) * 64 + lane];
    bf16x8 bh3 = B2h[(nt * 4 + 3) * 64 + lane];
    bf16x8 bl0 = B2l[(nt * 4 + 0) * 64 + lane];
    bf16x8 bl1 = B2l[(nt * 4 + 1) * 64 + lane];
    bf16x8 bl2 = B2l[(nt * 4 + 2) * 64 + lane];
    bf16x8 bl3 = B2l[(nt * 4 + 3) * 64 + lane];
    acc = MFMA16(hhf[0], bh0, acc);
    acc = MFMA16(hhf[1], bh1, acc);
    acc = MFMA16(hhf[2], bh2, acc);
    acc = MFMA16(hhf[3], bh3, acc);
    acc = MFMA16(hhf[0], bl0, acc);
    acc = MFMA16(hhf[1], bl1, acc);
    acc = MFMA16(hhf[2], bl2, acc);
    acc = MFMA16(hhf[3], bl3, acc);
    acc = MFMA16(hlf[0], bh0, acc);
    acc = MFMA16(hlf[1], bh1, acc);
    acc = MFMA16(hlf[2], bh2, acc);
    acc = MFMA16(hlf[3], bh3, acc);

    int j = nt * 16 + c;
    float bj = sb2[j];
    float o0 = fast_tanh(acc[0] + bj);
    float o1 = fast_tanh(acc[1] + bj);
    float o2 = fast_tanh(acc[2] + bj);
    float o3 = fast_tanh(acc[3] + bj);
    if (POOL) {
      if (uni) {
        float os = (o0 + o1) + (o2 + o3);
        os += __shfl_xor(os, 16);
        os += __shfl_xor(os, 32);
        if (g == 0) atomicAdd(&pooled[(size_t)b0 * DIM + j], os);
      } else {
        int mb = T * 16 + g * 4;
#pragma unroll
        for (int r = 0; r < 4; ++r) {
          int m = mb + r;
          float o = (r == 0) ? o0 : (r == 1) ? o1 : (r == 2) ? o2 : o3;
          if (m < n) atomicAdd(&pooled[(size_t)batch[m] * DIM + j], o);
        }
      }
    } else {
      int mb = T * 16 + g * 4;
      if (mb + 0 < n) houtb[(size_t)(mb + 0) * DIM + j] = f2bf(o0);
      if (mb + 1 < n) houtb[(size_t)(mb + 1) * DIM + j] = f2bf(o1);
      if (mb + 2 < n) houtb[(size_t)(mb + 2) * DIM + j] = f2bf(o2);
      if (mb + 3 < n) houtb[(size_t)(mb + 3) * DIM + j] = f2bf(o3);
    }
  }
}

// out[g][i] = tanh( (pooled[g]/max(cnt,1)) . linW[:,i] + linb[i] )
__global__ void k_out(const float* __restrict__ pooled, const int* __restrict__ cnt,
                      const float* __restrict__ linW, const float* __restrict__ linb,
                      float* __restrict__ out) {
  int g = blockIdx.x;
  int i = threadIdx.x;
  int c = cnt[g];
  float inv = 1.0f / (float)(c > 0 ? c : 1);
  float acc = 0.0f;
#pragma unroll
  for (int k = 0; k < DIM; ++k)
    acc += pooled[(size_t)g * DIM + k] * linW[k * DIM + i];
  out[(size_t)g * DIM + i] = fast_tanh(acc * inv + linb[i]);
}

extern "C" void kernel_launch(void* const* d_in, const int* in_sizes, int n_in,
                              void* d_out, int out_size, void* d_ws, size_t ws_size,
                              hipStream_t stream) {
  const float* x = (const float*)d_in[0];
  const int* ei = (const int*)d_in[1];
  const int* batch = (const int*)d_in[2];
  const float* eps1 = (const float*)d_in[3];
  const float* W11 = (const float*)d_in[4];
  const float* b11 = (const float*)d_in[5];
  const float* g1 = (const float*)d_in[6];
  const float* be1 = (const float*)d_in[7];
  const float* W12 = (const float*)d_in[8];
  const float* b12 = (const float*)d_in[9];
  const float* eps2 = (const float*)d_in[10];
  const float* W21 = (const float*)d_in[11];
  const float* b21 = (const float*)d_in[12];
  const float* g2 = (const float*)d_in[13];
  const float* be2 = (const float*)d_in[14];
  const float* W22 = (const float*)d_in[15];
  const float* b22 = (const float*)d_in[16];
  const float* linW = (const float*)d_in[17];
  const float* linb = (const float*)d_in[18];

  const int n = in_sizes[0] / DIM;  // 100000
  const int E = in_sizes[1] / 2;    // 1600000
  const int G = out_size / DIM;     // 256
  const int* src = ei;
  const int* dst = ei + E;
  const int NT = (n + 15) / 16;     // 6250
  const int npad = NT * 16;

  size_t off = 0;
  auto alloc = [&](size_t bytes) -> void* {
    void* p = (char*)d_ws + off;
    off += (bytes + 255) & ~(size_t)255;
    return p;
  };
  unsigned short* xb = (unsigned short*)alloc((size_t)npad * DIM * 2);
  unsigned short* h1b = (unsigned short*)alloc((size_t)npad * DIM * 2);
  float* vbuf = (float*)alloc((size_t)npad * DIM * 4);
  unsigned* regions = (unsigned*)alloc((size_t)NWB * NR * BCAP * 4);
  int* cnts_t = (int*)alloc((size_t)NWB * NR * 4);
  uint2* spill = (uint2*)alloc((size_t)65536 * 8);
  int* spilln = (int*)alloc(256);
  int* deg = (int*)alloc((size_t)n * 4);
  int* offs = (int*)alloc((size_t)n * 4);
  int* rbase = (int*)alloc(NR * 4);
  int* csr = (int*)alloc((size_t)E * 4);
  float* sc1 = (float*)alloc(TWO_DIM * 4);
  float* sh1 = (float*)alloc(TWO_DIM * 4);
  float* sc2 = (float*)alloc(TWO_DIM * 4);
  float* sh2 = (float*)alloc(TWO_DIM * 4);
  uint4* w1hA = (uint4*)alloc(1024 * 16);
  uint4* w1lA = (uint4*)alloc(1024 * 16);
  uint4* w2hA = (uint4*)alloc(1024 * 16);
  uint4* w2lA = (uint4*)alloc(1024 * 16);
  uint4* w1hB = (uint4*)alloc(1024 * 16);
  uint4* w1lB = (uint4*)alloc(1024 * 16);
  uint4* w2hB = (uint4*)alloc(1024 * 16);
  uint4* w2lB = (uint4*)alloc(1024 * 16);
  float* pooled = (float*)alloc((size_t)G * DIM * 4);
  int* cnt = (int*)alloc((size_t)G * 4);

  hipMemsetAsync(spilln, 0, 4, stream);

  const int N4 = n * DIM / 4;
  k_front<<<NWB + 18 + 1024, 256, 0, stream>>>(
      src, dst, regions, cnts_t, spilln, spill, E, n, x, xb, N4, W11, W12, W21, W22,
      b11, g1, be1, b21, g2, be2, batch, w1hA, w1lA, w2hA, w2lA, w1hB, w1lB, w2hB,
      w2lB, sc1, sh1, sc2, sh2, cnt);
  k_rtot<<<1, 1024, 0, stream>>>(cnts_t, spilln, spill, rbase, n);
  k_build<<<NR + 16, 1024, 0, stream>>>(regions, cnts_t, spilln, spill, rbase, deg,
                                        offs, csr, pooled, n);

  const int gB = (npad + 3) / 4;
  // GIN layer 1
  k_gatherv<<<gB, 256, 0, stream>>>(xb, csr, offs, deg, eps1, vbuf, n, npad);
  k_fused<false><<<(NT + 3) / 4, 256, 0, stream>>>(vbuf, w1hA, w1lA, w2hA, w2lA,
                                                   sc1, sh1, b12, h1b, nullptr,
                                                   nullptr, n, NT);
  // GIN layer 2
  k_gatherv<<<gB, 256, 0, stream>>>(h1b, csr, offs, deg, eps2, vbuf, n, npad);
  k_fused<true><<<(NT + 3) / 4, 256, 0, stream>>>(vbuf, w1hB, w1lB, w2hB, w2lB,
                                                  sc2, sh2, b22, nullptr, pooled,
                                                  batch, n, NT);
  k_out<<<G, DIM, 0, stream>>>(pooled, cnt, linW, linb, (float*)d_out);
}

// Round 23
// 221.440 us; speedup vs baseline: 1.1962x; 1.0854x over previous
//
#include <hip/hip_runtime.h>

#define DIM 64
#define TWO_DIM 128
#define NR 256     // node ranges (RS=391 < 512, fits 9-bit dstlocal)
#define BCAP 36    // per-(block,range) bucket capacity
#define NWB 512    // bucketing blocks

typedef __attribute__((ext_vector_type(8))) short bf16x8;
typedef __attribute__((ext_vector_type(4))) float f32x4;
#define MFMA16(A, B, C) __builtin_amdgcn_mfma_f32_16x16x32_bf16(A, B, C, 0, 0, 0)

__device__ __forceinline__ float fast_tanh(float x) {
  float cx = fminf(fmaxf(x, -15.0f), 15.0f);
  float e = __expf(2.0f * cx);
  return (e - 1.0f) / (e + 1.0f);
}

__device__ __forceinline__ unsigned short f2bf(float x) {
  unsigned int b = __float_as_uint(x);
  unsigned int r = b + 0x7FFFu + ((b >> 16) & 1u);
  return (unsigned short)(r >> 16);
}
__device__ __forceinline__ float bf2f(unsigned short h) {
  return __uint_as_float(((unsigned int)h) << 16);
}
__device__ __forceinline__ uint4 pack8(const unsigned short* s) {
  uint4 u;
  u.x = (unsigned)s[0] | ((unsigned)s[1] << 16);
  u.y = (unsigned)s[2] | ((unsigned)s[3] << 16);
  u.z = (unsigned)s[4] | ((unsigned)s[5] << 16);
  u.w = (unsigned)s[6] | ((unsigned)s[7] << 16);
  return u;
}

__device__ __forceinline__ void prepw_one(const float* __restrict__ W1,
                                          const float* __restrict__ W2,
                                          uint4* __restrict__ w1h, uint4* __restrict__ w1l,
                                          uint4* __restrict__ w2h, uint4* __restrict__ w2l,
                                          int p) {
  int lane = p & 63;
  int c = lane & 15, g = lane >> 4;
  unsigned short hh[8], ll[8];
  if (p < 1024) {
    int nt = p >> 7, f = (p >> 6) & 1;
    int nn = nt * 16 + c, kb = f * 32 + g * 8;
#pragma unroll
    for (int e = 0; e < 8; ++e) {
      float w = W1[(kb + e) * TWO_DIM + nn];
      hh[e] = f2bf(w);
      ll[e] = f2bf(w - bf2f(hh[e]));
    }
    w1h[p] = pack8(hh);
    w1l[p] = pack8(ll);
  } else {
    int q = p - 1024;
    int nt = q >> 8, f = (q >> 6) & 3;
    int nn = nt * 16 + c, kb = f * 32 + g * 8;
#pragma unroll
    for (int e = 0; e < 8; ++e) {
      float w = W2[(kb + e) * DIM + nn];
      hh[e] = f2bf(w);
      ll[e] = f2bf(w - bf2f(hh[e]));
    }
    w2h[q] = pack8(hh);
    w2l[q] = pack8(ll);
  }
}

// Front kernel: blocks [0,NWB) bucket edges into 256 ranges (packed
// src<<9|dstlocal; cnts stored TRANSPOSED cnts_t[r*NWB+wb]); [NWB,NWB+18)
// setup; rest fp32->bf16 conversion.
__global__ void k_front(const int* __restrict__ src, const int* __restrict__ dst,
                        unsigned* __restrict__ regions, int* __restrict__ cnts_t,
                        int* __restrict__ spilln, uint2* __restrict__ spill,
                        int E, int n,
                        const float* __restrict__ x, unsigned short* __restrict__ xb,
                        int N4,
                        const float* __restrict__ W11, const float* __restrict__ W12,
                        const float* __restrict__ W21, const float* __restrict__ W22,
                        const float* __restrict__ b11, const float* __restrict__ g1,
                        const float* __restrict__ be1, const float* __restrict__ b21,
                        const float* __restrict__ g2, const float* __restrict__ be2,
                        const int* __restrict__ batch,
                        uint4* __restrict__ w1hA, uint4* __restrict__ w1lA,
                        uint4* __restrict__ w2hA, uint4* __restrict__ w2lA,
                        uint4* __restrict__ w1hB, uint4* __restrict__ w1lB,
                        uint4* __restrict__ w2hB, uint4* __restrict__ w2lB,
                        float* __restrict__ sc1, float* __restrict__ sh1,
                        float* __restrict__ sc2, float* __restrict__ sh2,
                        int* __restrict__ cnt) {
  __shared__ int bcnt[NR];
  __shared__ int lb[257];
  const int b = blockIdx.x;
  const int t = threadIdx.x;

  if (b < NWB) {
    bcnt[t] = 0;
    __syncthreads();
    const int RS = (n + NR - 1) / NR;  // 391
    int tid = b * 256 + t;
    int stride = NWB * 256;
    int E4 = E >> 2;
    const int4* s4 = reinterpret_cast<const int4*>(src);
    const int4* d4 = reinterpret_cast<const int4*>(dst);
    unsigned* myreg = regions + (size_t)b * NR * BCAP;
    for (int i = tid; i < E4; i += stride) {
      int4 s = s4[i];
      int4 d = d4[i];
#pragma unroll
      for (int e = 0; e < 4; ++e) {
        int de = (e == 0) ? d.x : (e == 1) ? d.y : (e == 2) ? d.z : d.w;
        int se = (e == 0) ? s.x : (e == 1) ? s.y : (e == 2) ? s.z : s.w;
        int r = (unsigned)de / (unsigned)RS;
        int pos = atomicAdd(&bcnt[r], 1);
        if (pos < BCAP)
          myreg[r * BCAP + pos] =
              ((unsigned)se << 9) | (unsigned)(de - r * RS);
        else {
          int sp = atomicAdd(spilln, 1);
          spill[sp] = make_uint2((unsigned)se, (unsigned)de);
        }
      }
    }
    if (tid == 0) {
      for (int i = E4 << 2; i < E; ++i) {
        int sp = atomicAdd(spilln, 1);
        spill[sp] = make_uint2((unsigned)src[i], (unsigned)dst[i]);
      }
    }
    __syncthreads();
    cnts_t[(size_t)t * NWB + b] = min(bcnt[t], BCAP);
  } else if (b < NWB + 8) {
    prepw_one(W11, W12, w1hA, w1lA, w2hA, w2lA, (b - NWB) * 256 + t);
  } else if (b < NWB + 16) {
    prepw_one(W21, W22, w1hB, w1lB, w2hB, w2lB, (b - NWB - 8) * 256 + t);
  } else if (b == NWB + 16) {
    float rs = rsqrtf(1.0f + 1e-5f);
    if (t < TWO_DIM) {
      float s = g1[t] * rs;
      sc1[t] = s;
      sh1[t] = b11[t] * s + be1[t];
    } else {
      int i = t - TWO_DIM;
      float s = g2[i] * rs;
      sc2[i] = s;
      sh2[i] = b21[i] * s + be2[i];
    }
  } else if (b == NWB + 17) {
    int lo = 0, hi = n;
    while (lo < hi) {
      int mid = (lo + hi) >> 1;
      if (batch[mid] < t) lo = mid + 1; else hi = mid;
    }
    lb[t] = lo;
    if (t == 0) lb[256] = n;
    __syncthreads();
    cnt[t] = lb[t + 1] - lb[t];
  } else {
    int base = (b - NWB - 18) * 256 + t;
    int stride = (gridDim.x - NWB - 18) * 256;
    for (int i = base; i < N4; i += stride) {
      float4 f = reinterpret_cast<const float4*>(x)[i];
      ushort4 u;
      u.x = f2bf(f.x);
      u.y = f2bf(f.y);
      u.z = f2bf(f.z);
      u.w = f2bf(f.w);
      reinterpret_cast<ushort4*>(xb)[i] = u;
    }
  }
}

// Range totals + scan -> rbase (1 block, done ONCE). 4 threads per row,
// each summing a contiguous 128-entry run of cnts_t (L2-resident, 512 KB).
__global__ void k_rtot(const int* __restrict__ cnts_t, const int* __restrict__ spilln,
                       const uint2* __restrict__ spill, int* __restrict__ rbase,
                       int n) {
  __shared__ int ps[1024];
  __shared__ int tot[NR];
  __shared__ int sscan[NR];
  int t = threadIdx.x;
  int rr = t & 255, q = t >> 8;  // q in {0..3}
  const int* row = cnts_t + (size_t)rr * NWB + q * (NWB / 4);
  int sum = 0;
#pragma unroll 8
  for (int wb = 0; wb < NWB / 4; ++wb) sum += row[wb];
  ps[t] = sum;
  __syncthreads();
  if (t < NR) tot[t] = ps[t] + ps[t + 256] + ps[t + 512] + ps[t + 768];
  __syncthreads();
  if (t == 0) {
    int RS = (n + NR - 1) / NR;
    int sn = *spilln;
    for (int i = 0; i < sn; ++i) tot[spill[i].y / (unsigned)RS]++;
  }
  __syncthreads();
  if (t < NR) sscan[t] = tot[t];
  __syncthreads();
  for (int off = 1; off < NR; off <<= 1) {
    int u = (t >= off && t < NR) ? sscan[t - off] : 0;
    __syncthreads();
    if (t < NR) sscan[t] += u;
    __syncthreads();
  }
  if (t < NR) rbase[t] = sscan[t] - tot[t];
}

// One block per range (256 + 16 pooled-zero blocks). Coalesced cnts_t reads;
// precomputed rbase; LDS CSR build.
__launch_bounds__(1024, 8)
__global__ void k_build(const unsigned* __restrict__ regions, const int* __restrict__ cnts_t,
                        const int* __restrict__ spilln, const uint2* __restrict__ spill,
                        const int* __restrict__ rbase, int* __restrict__ deg,
                        int* __restrict__ offs, int* __restrict__ csr,
                        float* __restrict__ pooled, int n) {
  if (blockIdx.x >= NR) {
    int i = (blockIdx.x - NR) * 1024 + threadIdx.x;
    pooled[i] = 0.0f;
    return;
  }
  __shared__ unsigned lbuf[8192];  // 32 KB (avg 6250 entries/range)
  __shared__ int ccnt[NWB];
  __shared__ int co[NWB];
  __shared__ int ps[1024];
  __shared__ int ldeg[400];
  __shared__ int lcur[400];
  __shared__ int sTr;
  const int r = blockIdx.x;
  const int RS = (n + NR - 1) / NR;  // 391
  const int lo = r * RS;
  const int hi = min(n, lo + RS);
  const int len = hi - lo;
  int t = threadIdx.x;
  const int myrbase = rbase[r];

  if (t < NWB) ccnt[t] = cnts_t[(size_t)r * NWB + t];  // coalesced
  __syncthreads();
  int own = (t < NWB) ? ccnt[t] : 0;
  ps[t] = own;
  __syncthreads();
  for (int off = 1; off < 1024; off <<= 1) {
    int u = (t >= off) ? ps[t - off] : 0;
    __syncthreads();
    ps[t] += u;
    __syncthreads();
  }
  if (t < NWB) co[t] = ps[t] - own;
  int total = ps[1023];
  __syncthreads();

  const int wave = t >> 6, lane = t & 63;
  for (int wb = wave; wb < NWB; wb += 16) {
    int c = ccnt[wb];
    const unsigned* reg = regions + ((size_t)wb * NR + r) * BCAP;
    int o = co[wb];
    for (int i = lane; i < c; i += 64) lbuf[o + i] = reg[i];
  }
  if (t == 0) {
    int Tr = total;
    int sn = *spilln;
    for (int i = 0; i < sn; ++i) {
      uint2 e = spill[i];
      int dv = (int)e.y;
      if (dv >= lo && dv < hi && Tr < 8192)
        lbuf[Tr++] = (e.x << 9) | (unsigned)(dv - lo);
    }
    sTr = Tr;
  }
  if (t < len) ldeg[t] = 0;
  __syncthreads();
  const int Tr = sTr;

  for (int i = t; i < Tr; i += 1024) atomicAdd(&ldeg[lbuf[i] & 511u], 1);
  __syncthreads();

  int d = (t < len) ? ldeg[t] : 0;
  ps[t] = d;
  __syncthreads();
  for (int off = 1; off < 1024; off <<= 1) {
    int u = (t >= off) ? ps[t - off] : 0;
    __syncthreads();
    ps[t] += u;
    __syncthreads();
  }
  int base = myrbase + ps[t] - d;
  if (t < len) {
    offs[lo + t] = base;
    deg[lo + t] = d;
    lcur[t] = base;
  }
  __syncthreads();

  for (int i = t; i < Tr; i += 1024) {
    unsigned e = lbuf[i];
    int p = atomicAdd(&lcur[e & 511u], 1);
    csr[p] = (int)(e >> 9);
  }
}

// Gather + GIN pre-sum from bf16 rows, scalarized index stream.
__global__ void k_gatherv(const unsigned short* __restrict__ xb,
                          const int* __restrict__ csr, const int* __restrict__ offs,
                          const int* __restrict__ deg, const float* __restrict__ epsp,
                          float* __restrict__ v, int n, int npad) {
  int node = __builtin_amdgcn_readfirstlane(blockIdx.x * 4 + (threadIdx.x >> 6));
  int t = threadIdx.x & 63;
  if (node >= npad) return;
  if (node >= n) {
    v[(size_t)node * DIM + t] = 0.0f;
    return;
  }
  int s = offs[node], d = deg[node];
  float a0 = 0.f, a1 = 0.f, a2 = 0.f, a3 = 0.f;
  float a4 = 0.f, a5 = 0.f, a6 = 0.f, a7 = 0.f;
  int i = 0;
  for (; i + 16 <= d; i += 16) {
    int s0 = csr[s + i + 0];
    int s1 = csr[s + i + 1];
    int s2 = csr[s + i + 2];
    int s3 = csr[s + i + 3];
    int s4 = csr[s + i + 4];
    int s5 = csr[s + i + 5];
    int s6 = csr[s + i + 6];
    int s7 = csr[s + i + 7];
    int s8 = csr[s + i + 8];
    int s9 = csr[s + i + 9];
    int sa = csr[s + i + 10];
    int sb = csr[s + i + 11];
    int sc = csr[s + i + 12];
    int sd = csr[s + i + 13];
    int se = csr[s + i + 14];
    int sf = csr[s + i + 15];
    unsigned short w0 = xb[(size_t)s0 * DIM + t];
    unsigned short w1 = xb[(size_t)s1 * DIM + t];
    unsigned short w2 = xb[(size_t)s2 * DIM + t];
    unsigned short w3 = xb[(size_t)s3 * DIM + t];
    unsigned short w4 = xb[(size_t)s4 * DIM + t];
    unsigned short w5 = xb[(size_t)s5 * DIM + t];
    unsigned short w6 = xb[(size_t)s6 * DIM + t];
    unsigned short w7 = xb[(size_t)s7 * DIM + t];
    unsigned short w8 = xb[(size_t)s8 * DIM + t];
    unsigned short w9 = xb[(size_t)s9 * DIM + t];
    unsigned short wa = xb[(size_t)sa * DIM + t];
    unsigned short wb = xb[(size_t)sb * DIM + t];
    unsigned short wc = xb[(size_t)sc * DIM + t];
    unsigned short wd = xb[(size_t)sd * DIM + t];
    unsigned short we = xb[(size_t)se * DIM + t];
    unsigned short wf = xb[(size_t)sf * DIM + t];
    a0 += bf2f(w0); a1 += bf2f(w1); a2 += bf2f(w2); a3 += bf2f(w3);
    a4 += bf2f(w4); a5 += bf2f(w5); a6 += bf2f(w6); a7 += bf2f(w7);
    a0 += bf2f(w8); a1 += bf2f(w9); a2 += bf2f(wa); a3 += bf2f(wb);
    a4 += bf2f(wc); a5 += bf2f(wd); a6 += bf2f(we); a7 += bf2f(wf);
  }
  if (i + 8 <= d) {
    int s0 = csr[s + i + 0];
    int s1 = csr[s + i + 1];
    int s2 = csr[s + i + 2];
    int s3 = csr[s + i + 3];
    int s4 = csr[s + i + 4];
    int s5 = csr[s + i + 5];
    int s6 = csr[s + i + 6];
    int s7 = csr[s + i + 7];
    unsigned short w0 = xb[(size_t)s0 * DIM + t];
    unsigned short w1 = xb[(size_t)s1 * DIM + t];
    unsigned short w2 = xb[(size_t)s2 * DIM + t];
    unsigned short w3 = xb[(size_t)s3 * DIM + t];
    unsigned short w4 = xb[(size_t)s4 * DIM + t];
    unsigned short w5 = xb[(size_t)s5 * DIM + t];
    unsigned short w6 = xb[(size_t)s6 * DIM + t];
    unsigned short w7 = xb[(size_t)s7 * DIM + t];
    a0 += bf2f(w0); a1 += bf2f(w1); a2 += bf2f(w2); a3 += bf2f(w3);
    a4 += bf2f(w4); a5 += bf2f(w5); a6 += bf2f(w6); a7 += bf2f(w7);
    i += 8;
  }
  if (i + 4 <= d) {
    int s0 = csr[s + i + 0];
    int s1 = csr[s + i + 1];
    int s2 = csr[s + i + 2];
    int s3 = csr[s + i + 3];
    unsigned short w0 = xb[(size_t)s0 * DIM + t];
    unsigned short w1 = xb[(size_t)s1 * DIM + t];
    unsigned short w2 = xb[(size_t)s2 * DIM + t];
    unsigned short w3 = xb[(size_t)s3 * DIM + t];
    a0 += bf2f(w0); a1 += bf2f(w1); a2 += bf2f(w2); a3 += bf2f(w3);
    i += 4;
  }
  for (; i < d; ++i) {
    int sn = csr[s + i];
    a0 += bf2f(xb[(size_t)sn * DIM + t]);
  }
  float ep = 1.0f + epsp[0];
  v[(size_t)node * DIM + t] =
      ep * bf2f(xb[(size_t)node * DIM + t]) +
      (((a0 + a1) + (a2 + a3)) + ((a4 + a5) + (a6 + a7)));
}

// Fused GIN MLP (unchanged).
template <bool POOL>
__launch_bounds__(256, 2)
__global__ void k_fused(const float* __restrict__ vbuf,
                        const uint4* __restrict__ w1h, const uint4* __restrict__ w1l,
                        const uint4* __restrict__ w2h, const uint4* __restrict__ w2l,
                        const float* __restrict__ sc, const float* __restrict__ sh,
                        const float* __restrict__ b2, unsigned short* __restrict__ houtb,
                        float* __restrict__ pooled, const int* __restrict__ batch,
                        int n, int NTiles) {
  __shared__ uint4 sB1h[1024], sB1l[1024];
  __shared__ uint4 sB2h[1024], sB2l[1024];
  __shared__ float ssc[TWO_DIM], ssh[TWO_DIM], sb2[DIM];
  __shared__ float sHc[4][16 * 36];

  int t = threadIdx.x;
#pragma unroll
  for (int q = 0; q < 4; ++q) {
    sB1h[q * 256 + t] = w1h[q * 256 + t];
    sB1l[q * 256 + t] = w1l[q * 256 + t];
    sB2h[q * 256 + t] = w2h[q * 256 + t];
    sB2l[q * 256 + t] = w2l[q * 256 + t];
  }
  if (t < TWO_DIM) {
    ssc[t] = sc[t];
    ssh[t] = sh[t];
  }
  if (t < DIM) sb2[t] = b2[t];
  __syncthreads();

  const int wid = t >> 6, lane = t & 63;
  const int T = blockIdx.x * 4 + wid;
  if (T >= NTiles) return;
  const int c = lane & 15, g = lane >> 4;

  bf16x8 vah0, vah1, val0, val1;
  {
    const float* vr = vbuf + (size_t)(T * 16 + c) * DIM + g * 8;
    float4 q0 = *reinterpret_cast<const float4*>(vr);
    float4 q1 = *reinterpret_cast<const float4*>(vr + 4);
    float4 q2 = *reinterpret_cast<const float4*>(vr + 32);
    float4 q3 = *reinterpret_cast<const float4*>(vr + 36);
    float f0[8] = {q0.x, q0.y, q0.z, q0.w, q1.x, q1.y, q1.z, q1.w};
    float f1[8] = {q2.x, q2.y, q2.z, q2.w, q3.x, q3.y, q3.z, q3.w};
    unsigned short h0[8], l0[8], h1[8], l1[8];
#pragma unroll
    for (int e = 0; e < 8; ++e) {
      h0[e] = f2bf(f0[e]);
      l0[e] = f2bf(f0[e] - bf2f(h0[e]));
      h1[e] = f2bf(f1[e]);
      l1[e] = f2bf(f1[e] - bf2f(h1[e]));
    }
    uint4 u0 = pack8(h0), u1 = pack8(h1), u2 = pack8(l0), u3 = pack8(l1);
    vah0 = *reinterpret_cast<bf16x8*>(&u0);
    vah1 = *reinterpret_cast<bf16x8*>(&u1);
    val0 = *reinterpret_cast<bf16x8*>(&u2);
    val1 = *reinterpret_cast<bf16x8*>(&u3);
  }

  const bf16x8* B1h = reinterpret_cast<const bf16x8*>(sB1h);
  const bf16x8* B1l = reinterpret_cast<const bf16x8*>(sB1l);
  const bf16x8* B2h = reinterpret_cast<const bf16x8*>(sB2h);
  const bf16x8* B2l = reinterpret_cast<const bf16x8*>(sB2l);
  float* myH = &sHc[wid][0];

  bf16x8 hhf[4], hlf[4];
#pragma unroll
  for (int f2 = 0; f2 < 4; ++f2) {
#pragma unroll
    for (int q = 0; q < 2; ++q) {
      int nt = 2 * f2 + q;
      f32x4 acc = {0.f, 0.f, 0.f, 0.f};
      bf16x8 bh0 = B1h[(nt * 2 + 0) * 64 + lane];
      bf16x8 bl0 = B1l[(nt * 2 + 0) * 64 + lane];
      bf16x8 bh1 = B1h[(nt * 2 + 1) * 64 + lane];
      bf16x8 bl1 = B1l[(nt * 2 + 1) * 64 + lane];
      acc = MFMA16(vah0, bh0, acc);
      acc = MFMA16(vah1, bh1, acc);
      acc = MFMA16(vah0, bl0, acc);
      acc = MFMA16(vah1, bl1, acc);
      acc = MFMA16(val0, bh0, acc);
      acc = MFMA16(val1, bh1, acc);
      int j = nt * 16 + c;
      float scj = ssc[j], shj = ssh[j];
#pragma unroll
      for (int r = 0; r < 4; ++r)
        myH[(g * 4 + r) * 36 + q * 16 + c] = fast_tanh(acc[r] * scj + shj);
    }
    const float* hp = myH + c * 36 + g * 8;
    float4 v0 = *reinterpret_cast<const float4*>(hp);
    float4 v1 = *reinterpret_cast<const float4*>(hp + 4);
    float vv[8] = {v0.x, v0.y, v0.z, v0.w, v1.x, v1.y, v1.z, v1.w};
    unsigned short H8[8], L8[8];
#pragma unroll
    for (int e = 0; e < 8; ++e) {
      H8[e] = f2bf(vv[e]);
      L8[e] = f2bf(vv[e] - bf2f(H8[e]));
    }
    uint4 uh = pack8(H8), ul = pack8(L8);
    hhf[f2] = *reinterpret_cast<bf16x8*>(&uh);
    hlf[f2] = *reinterpret_cast<bf16x8*>(&ul);
  }

  bool uni = false;
  int b0 = 0;
  if (POOL) {
    b0 = batch[min(T * 16, n - 1)];
    int b15 = batch[min(T * 16 + 15, n - 1)];
    uni = (b0 == b15) && (T * 16 + 15 < n);
  }

#pragma unroll
  for (int nt = 0; nt < 4; ++nt) {
    f32x4 acc = {0.f, 0.f, 0.f, 0.f};
    bf16x8 bh0 = B2h[(nt * 4 + 0) * 64 + lane];
    bf16x8 bh1 = B2h[(nt * 4 + 1) * 64 + lane];
    bf16x8 bh2 = B2h[(nt * 4 + 2) * 64 + lane];
    bf16x8 bh3 = B2h[(nt * 4 + 3) * 64 + lane];
    bf16x8 bl0 = B2l[(nt * 4 + 0) * 64 + lane];
    bf16x8 bl1 = B2l[(nt * 4 + 1) * 64 + lane];
    bf16x8 bl2 = B2l[(nt * 4 + 2) * 64 + lane];
    bf16x8 bl3 = B2l[(nt * 4 + 3) * 64 + lane];
    acc = MFMA16(hhf[0], bh0, acc);
    acc = MFMA16(hhf[1], bh1, acc);
    acc = MFMA16(hhf[2], bh2, acc);
    acc = MFMA16(hhf[3], bh3, acc);
    acc = MFMA16(hhf[0], bl0, acc);
    acc = MFMA16(hhf[1], bl1, acc);
    acc = MFMA16(hhf[2], bl2, acc);
    acc = MFMA16(hhf[3], bl3, acc);
    acc = MFMA16(hlf[0], bh0, acc);
    acc = MFMA16(hlf[1], bh1, acc);
    acc = MFMA16(hlf[2], bh2, acc);
    acc = MFMA16(hlf[3], bh3, acc);

    int j = nt * 16 + c;
    float bj = sb2[j];
    float o0 = fast_tanh(acc[0] + bj);
    float o1 = fast_tanh(acc[1] + bj);
    float o2 = fast_tanh(acc[2] + bj);
    float o3 = fast_tanh(acc[3] + bj);
    if (POOL) {
      if (uni) {
        float os = (o0 + o1) + (o2 + o3);
        os += __shfl_xor(os, 16);
        os += __shfl_xor(os, 32);
        if (g == 0) atomicAdd(&pooled[(size_t)b0 * DIM + j], os);
      } else {
        int mb = T * 16 + g * 4;
#pragma unroll
        for (int r = 0; r < 4; ++r) {
          int m = mb + r;
          float o = (r == 0) ? o0 : (r == 1) ? o1 : (r == 2) ? o2 : o3;
          if (m < n) atomicAdd(&pooled[(size_t)batch[m] * DIM + j], o);
        }
      }
    } else {
      int mb = T * 16 + g * 4;
      if (mb + 0 < n) houtb[(size_t)(mb + 0) * DIM + j] = f2bf(o0);
      if (mb + 1 < n) houtb[(size_t)(mb + 1) * DIM + j] = f2bf(o1);
      if (mb + 2 < n) houtb[(size_t)(mb + 2) * DIM + j] = f2bf(o2);
      if (mb + 3 < n) houtb[(size_t)(mb + 3) * DIM + j] = f2bf(o3);
    }
  }
}

// out[g][i] = tanh( (pooled[g]/max(cnt,1)) . linW[:,i] + linb[i] )
__global__ void k_out(const float* __restrict__ pooled, const int* __restrict__ cnt,
                      const float* __restrict__ linW, const float* __restrict__ linb,
                      float* __restrict__ out) {
  int g = blockIdx.x;
  int i = threadIdx.x;
  int c = cnt[g];
  float inv = 1.0f / (float)(c > 0 ? c : 1);
  float acc = 0.0f;
#pragma unroll
  for (int k = 0; k < DIM; ++k)
    acc += pooled[(size_t)g * DIM + k] * linW[k * DIM + i];
  out[(size_t)g * DIM + i] = fast_tanh(acc * inv + linb[i]);
}

extern "C" void kernel_launch(void* const* d_in, const int* in_sizes, int n_in,
                              void* d_out, int out_size, void* d_ws, size_t ws_size,
                              hipStream_t stream) {
  const float* x = (const float*)d_in[0];
  const int* ei = (const int*)d_in[1];
  const int* batch = (const int*)d_in[2];
  const float* eps1 = (const float*)d_in[3];
  const float* W11 = (const float*)d_in[4];
  const float* b11 = (const float*)d_in[5];
  const float* g1 = (const float*)d_in[6];
  const float* be1 = (const float*)d_in[7];
  const float* W12 = (const float*)d_in[8];
  const float* b12 = (const float*)d_in[9];
  const float* eps2 = (const float*)d_in[10];
  const float* W21 = (const float*)d_in[11];
  const float* b21 = (const float*)d_in[12];
  const float* g2 = (const float*)d_in[13];
  const float* be2 = (const float*)d_in[14];
  const float* W22 = (const float*)d_in[15];
  const float* b22 = (const float*)d_in[16];
  const float* linW = (const float*)d_in[17];
  const float* linb = (const float*)d_in[18];

  const int n = in_sizes[0] / DIM;  // 100000
  const int E = in_sizes[1] / 2;    // 1600000
  const int G = out_size / DIM;     // 256
  const int* src = ei;
  const int* dst = ei + E;
  const int NT = (n + 15) / 16;     // 6250
  const int npad = NT * 16;

  size_t off = 0;
  auto alloc = [&](size_t bytes) -> void* {
    void* p = (char*)d_ws + off;
    off += (bytes + 255) & ~(size_t)255;
    return p;
  };
  unsigned short* xb = (unsigned short*)alloc((size_t)npad * DIM * 2);
  unsigned short* h1b = (unsigned short*)alloc((size_t)npad * DIM * 2);
  float* vbuf = (float*)alloc((size_t)npad * DIM * 4);
  unsigned* regions = (unsigned*)alloc((size_t)NWB * NR * BCAP * 4);
  int* cnts_t = (int*)alloc((size_t)NWB * NR * 4);
  uint2* spill = (uint2*)alloc((size_t)65536 * 8);
  int* spilln = (int*)alloc(256);
  int* deg = (int*)alloc((size_t)n * 4);
  int* offs = (int*)alloc((size_t)n * 4);
  int* rbase = (int*)alloc(NR * 4);
  int* csr = (int*)alloc((size_t)E * 4);
  float* sc1 = (float*)alloc(TWO_DIM * 4);
  float* sh1 = (float*)alloc(TWO_DIM * 4);
  float* sc2 = (float*)alloc(TWO_DIM * 4);
  float* sh2 = (float*)alloc(TWO_DIM * 4);
  uint4* w1hA = (uint4*)alloc(1024 * 16);
  uint4* w1lA = (uint4*)alloc(1024 * 16);
  uint4* w2hA = (uint4*)alloc(1024 * 16);
  uint4* w2lA = (uint4*)alloc(1024 * 16);
  uint4* w1hB = (uint4*)alloc(1024 * 16);
  uint4* w1lB = (uint4*)alloc(1024 * 16);
  uint4* w2hB = (uint4*)alloc(1024 * 16);
  uint4* w2lB = (uint4*)alloc(1024 * 16);
  float* pooled = (float*)alloc((size_t)G * DIM * 4);
  int* cnt = (int*)alloc((size_t)G * 4);

  hipMemsetAsync(spilln, 0, 4, stream);

  const int N4 = n * DIM / 4;
  k_front<<<NWB + 18 + 1024, 256, 0, stream>>>(
      src, dst, regions, cnts_t, spilln, spill, E, n, x, xb, N4, W11, W12, W21, W22,
      b11, g1, be1, b21, g2, be2, batch, w1hA, w1lA, w2hA, w2lA, w1hB, w1lB, w2hB,
      w2lB, sc1, sh1, sc2, sh2, cnt);
  k_rtot<<<1, 1024, 0, stream>>>(cnts_t, spilln, spill, rbase, n);
  k_build<<<NR + 16, 1024, 0, stream>>>(regions, cnts_t, spilln, spill, rbase, deg,
                                        offs, csr, pooled, n);

  const int gB = (npad + 3) / 4;
  // GIN layer 1
  k_gatherv<<<gB, 256, 0, stream>>>(xb, csr, offs, deg, eps1, vbuf, n, npad);
  k_fused<false><<<(NT + 3) / 4, 256, 0, stream>>>(vbuf, w1hA, w1lA, w2hA, w2lA,
                                                   sc1, sh1, b12, h1b, nullptr,
                                                   nullptr, n, NT);
  // GIN layer 2
  k_gatherv<<<gB, 256, 0, stream>>>(h1b, csr, offs, deg, eps2, vbuf, n, npad);
  k_fused<true><<<(NT + 3) / 4, 256, 0, stream>>>(vbuf, w1hB, w1lB, w2hB, w2lB,
                                                  sc2, sh2, b22, nullptr, pooled,
                                                  batch, n, NT);
  k_out<<<G, DIM, 0, stream>>>(pooled, cnt, linW, linb, (float*)d_out);
}